// Round 16
// baseline (85.685 us; speedup 1.0000x reference)
//
#include <hip/hip_runtime.h>
#include <hip/hip_bf16.h>

#define NV 512
#define NF 64

typedef __attribute__((ext_vector_type(8))) short bf16x8;
typedef __attribute__((ext_vector_type(4))) float f32x4;

union BF8 { bf16x8 v; unsigned u[4]; };

// packed f32 pair -> bf16 pair (RNE); maps to v_cvt_pk_bf16_f32
__device__ __forceinline__ unsigned cvt2(float lo, float hi) {
    __hip_bfloat162 p = __float22bfloat162_rn(float2{lo, hi});
    return *reinterpret_cast<unsigned*>(&p);
}
__device__ __forceinline__ unsigned short cvt1(float x) {
    __hip_bfloat16 b = __float2bfloat16(x);
    return *reinterpret_cast<unsigned short*>(&b);
}

// AwT byte address: row f (1KB each); XOR-swz mixes f bits 0-2 and 3-5.
__device__ __forceinline__ unsigned awt_addr(int f, int jbyte) {
    return (unsigned)((f * 1024 + jbyte) ^ (((f ^ (f >> 3)) & 7) << 4));
}
// scr slot: slot>>1 distinct over write groups {r,r+4,r+8,r+12}; 2-uniform overall.
__device__ __forceinline__ int slot2(int row) {
    return 2 * (((row >> 2) ^ row) & 3) + (row & 1);
}

__global__ void k_edges(const int* __restrict__ ei, int E, unsigned int* __restrict__ mask) {
    int e = blockIdx.x * 256 + threadIdx.x;
    if (e < E) {
        int s = ei[e];       // src
        int d = ei[E + e];   // dst
        atomicOr(&mask[d * 16 + (s >> 5)], 1u << (s & 31));
    }
}

// 4 waves per v: wave g scans mask words 4g..4g+3; LDS reduce.
__global__ void k_S(const unsigned int* __restrict__ mask, const float* __restrict__ alpha,
                    float* __restrict__ S) {
    __shared__ float red[4][64];
    int v = blockIdx.x;
    int lane = threadIdx.x & 63;
    int g = threadIdx.x >> 6;
    float a0 = 0.f, a1 = 0.f;
    for (int wd = g * 4; wd < g * 4 + 4; ++wd) {
        unsigned bits = mask[v * 16 + wd];
        while (bits) {
            int b0 = __ffs(bits) - 1; bits &= bits - 1;
            float x0 = alpha[((size_t)v * NV + wd * 32 + b0) * NF + lane];
            if (bits) {
                int b1 = __ffs(bits) - 1; bits &= bits - 1;
                a1 += alpha[((size_t)v * NV + wd * 32 + b1) * NF + lane];
            }
            a0 += x0;
        }
    }
    red[g][lane] = a0 + a1;
    __syncthreads();
    if (g == 0)
        S[v * NF + lane] = red[0][lane] + red[1][lane] + red[2][lane] + red[3][lane];
}

// LDS 64KB: AwT bf16 [64 f][512 j] swizzled (GEMM phase); post-GEMM the region is
// dead and [0,16K) is reused as per-wave scr (2KB/wave, slot2 swz). Weights in
// registers. rv residuals for ALL 4 m-tiles issue right after staging loads so
// their L3/HBM latency hides under staging + GEMM (~30us of program distance).
__global__ __launch_bounds__(512, 2) void k_main(
    const float* __restrict__ alpha, const float* __restrict__ w1, const float* __restrict__ b1,
    const float* __restrict__ w2, const float* __restrict__ b2, const float* __restrict__ eps_p,
    const unsigned int* __restrict__ mask, const float* __restrict__ S,
    float* __restrict__ out)
{
    extern __shared__ char smem[];
    const int w    = blockIdx.x;
    const int t    = threadIdx.x;
    const int lane = t & 63;
    const int wid  = t >> 6;
    const int nlo  = lane & 15;
    const int g    = lane >> 4;
    const int kbase = g * 8;
    const int mbase = wid * 64;
    const float* src = alpha + (size_t)w * (NV * NF);

    auto stage_half = [&](int i) {
        int task = i * 512 + t;
        int jb = task >> 4;
        int fq = task & 15;
        unsigned ua[4][4];
#pragma unroll
        for (int h = 0; h < 4; ++h) {
            f32x4 r0 = *(const f32x4*)(src + (size_t)(jb * 8 + 2 * h) * NF + fq * 4);
            f32x4 r1 = *(const f32x4*)(src + (size_t)(jb * 8 + 2 * h + 1) * NF + fq * 4);
#pragma unroll
            for (int c = 0; c < 4; ++c)
                ua[c][h] = cvt2(r0[c], r1[c]);    // v_cvt_pk_bf16_f32
        }
#pragma unroll
        for (int c = 0; c < 4; ++c) {
            BF8 p;
            p.u[0] = ua[c][0]; p.u[1] = ua[c][1]; p.u[2] = ua[c][2]; p.u[3] = ua[c][3];
            *(bf16x8*)(smem + awt_addr(fq * 4 + c, jb * 16)) = p.v;
        }
    };

    f32x4 acc[4][4];

    // phase 1a: stage half0 (cold-HBM loads issue first)
    stage_half(0);

    // phase 1b: EARLY-ISSUE all residual rv loads (independent of everything;
    // 64 regs; consumed only in the epilogue ~30us later -> latency fully hidden)
    float rvv[4][4][4];   // [mi][nt][r]
#pragma unroll
    for (int mi = 0; mi < 4; ++mi)
#pragma unroll
        for (int nt = 0; nt < 4; ++nt)
#pragma unroll
            for (int r = 0; r < 4; ++r)
                rvv[mi][nt][r] =
                    alpha[((size_t)(mbase + mi * 16 + g * 4 + r) * NV + w) * NF + nt * 16 + nlo];

    // phase 1c: init acc from S (C-in of first MFMA)
#pragma unroll
    for (int mi = 0; mi < 4; ++mi)
#pragma unroll
        for (int nt = 0; nt < 4; ++nt)
#pragma unroll
            for (int r = 0; r < 4; ++r)
                acc[mi][nt][r] = S[(size_t)(mbase + mi * 16 + g * 4 + r) * NF + nt * 16 + nlo];

    __syncthreads();

    // adjacency GEMM over one kq; mask words per-kq transient (L2-hot, R7-proven)
    auto gemm_q = [&](int kq) {
        uint4 qm[4];
#pragma unroll
        for (int mi = 0; mi < 4; ++mi)
            qm[mi] = *(const uint4*)(mask + (size_t)(mbase + mi * 16 + nlo) * 16 + kq * 4);
#pragma unroll
        for (int kr = 0; kr < 4; ++kr) {
            const int kk = kq * 4 + kr;
            BF8 afr[4];
#pragma unroll
            for (int mi = 0; mi < 4; ++mi) {
                unsigned byteb = ((&qm[mi].x)[kr] >> (g * 8)) & 0xFFu;
#pragma unroll
                for (int h = 0; h < 4; ++h) {
                    unsigned b0 = (byteb >> (2 * h)) & 1u;
                    unsigned b1 = (byteb >> (2 * h + 1)) & 1u;
                    afr[mi].u[h] = (b0 ? 0x3F80u : 0u) | (b1 ? 0x3F800000u : 0u);
                }
            }
#pragma unroll
            for (int nt = 0; nt < 4; ++nt) {
                bf16x8 bfr = *(const bf16x8*)(smem + awt_addr(nt * 16 + nlo, kk * 64 + g * 16));
#pragma unroll
                for (int mi = 0; mi < 4; ++mi)
                    acc[mi][nt] = __builtin_amdgcn_mfma_f32_16x16x32_bf16(afr[mi].v, bfr, acc[mi][nt], 0, 0, 0);
            }
        }
    };

    // pipeline: {stage half1 || GEMM kq0-1 (half0 only)} | barrier | GEMM kq2-3
    stage_half(1);
    gemm_q(0); gemm_q(1);
    __syncthreads();
    gemm_q(2); gemm_q(3);

    // weight frags -> registers (batch issues; drains at the barrier below)
    bf16x8 w1f[2][4], w2f[2][4];
#pragma unroll
    for (int ks = 0; ks < 2; ++ks)
#pragma unroll
        for (int nt = 0; nt < 4; ++nt) {
            bf16x8 a, bb;
#pragma unroll
            for (int e = 0; e < 8; ++e) {
                int k = ks * 32 + kbase + e;
                a[e]  = (short)cvt1(w1[k * NF + nt * 16 + nlo]);
                bb[e] = (short)cvt1(w2[k * NF + nt * 16 + nlo]);
            }
            w1f[ks][nt] = a;
            w2f[ks][nt] = bb;
        }
    float b1v[4], b2v[4];
#pragma unroll
    for (int nt = 0; nt < 4; ++nt) {
        b1v[nt] = b1[nt * 16 + nlo];
        b2v[nt] = b2[nt * 16 + nlo];
    }
    const float ceps = 1.0f + eps_p[0];

    __syncthreads();   // all AwT reads done; [0,16K) reusable as scr

    char* myscr = smem + wid * 2048;   // [16][64] bf16, slot2 swz
#pragma unroll
    for (int mi = 0; mi < 4; ++mi) {
        int v0 = mbase + mi * 16;
#pragma unroll
        for (int nt = 0; nt < 4; ++nt)
#pragma unroll
            for (int r = 0; r < 4; ++r) {
                float pre = acc[mi][nt][r] + ceps * rvv[mi][nt][r];   // rv already resident
                int row = g * 4 + r;
                *(unsigned short*)(myscr + row * 128 + ((2 * (nt * 16 + nlo)) ^ (slot2(row) << 4))) = cvt1(pre);
            }

        // layer 1 (A from scr; B = w1f regs)
        bf16x8 a0 = *(const bf16x8*)(myscr + nlo * 128 + ((g * 16) ^ (slot2(nlo) << 4)));
        bf16x8 a1 = *(const bf16x8*)(myscr + nlo * 128 + ((g * 16 + 64) ^ (slot2(nlo) << 4)));
        f32x4 accm[4];
#pragma unroll
        for (int nt = 0; nt < 4; ++nt) {
            f32x4 z = {0.f, 0.f, 0.f, 0.f};
            z = __builtin_amdgcn_mfma_f32_16x16x32_bf16(a0, w1f[0][nt], z, 0, 0, 0);
            z = __builtin_amdgcn_mfma_f32_16x16x32_bf16(a1, w1f[1][nt], z, 0, 0, 0);
            accm[nt] = z;
        }

        // relu + b1 -> scr
#pragma unroll
        for (int nt = 0; nt < 4; ++nt)
#pragma unroll
            for (int r = 0; r < 4; ++r) {
                float hv = accm[nt][r] + b1v[nt];
                hv = hv > 0.f ? hv : 0.f;
                int row = g * 4 + r;
                *(unsigned short*)(myscr + row * 128 + ((2 * (nt * 16 + nlo)) ^ (slot2(row) << 4))) = cvt1(hv);
            }

        // layer 2 (B = w2f regs)
        bf16x8 h0 = *(const bf16x8*)(myscr + nlo * 128 + ((g * 16) ^ (slot2(nlo) << 4)));
        bf16x8 h1 = *(const bf16x8*)(myscr + nlo * 128 + ((g * 16 + 64) ^ (slot2(nlo) << 4)));
#pragma unroll
        for (int nt = 0; nt < 4; ++nt) {
            f32x4 z = {0.f, 0.f, 0.f, 0.f};
            z = __builtin_amdgcn_mfma_f32_16x16x32_bf16(h0, w2f[0][nt], z, 0, 0, 0);
            z = __builtin_amdgcn_mfma_f32_16x16x32_bf16(h1, w2f[1][nt], z, 0, 0, 0);
#pragma unroll
            for (int r = 0; r < 4; ++r) {
                int vv = v0 + g * 4 + r;
                out[((size_t)vv * NV + w) * NF + nt * 16 + nlo] = z[r] + b2v[nt];
            }
        }
    }
}

extern "C" void kernel_launch(void* const* d_in, const int* in_sizes, int n_in,
                              void* d_out, int out_size, void* d_ws, size_t ws_size,
                              hipStream_t stream) {
    const float* alpha = (const float*)d_in[0];
    const int*   ei    = (const int*)d_in[1];
    const float* w1    = (const float*)d_in[2];
    const float* b1    = (const float*)d_in[3];
    const float* w2    = (const float*)d_in[4];
    const float* b2    = (const float*)d_in[5];
    const float* eps   = (const float*)d_in[6];
    float* out = (float*)d_out;
    int E = in_sizes[1] / 2;

    // ws layout (bytes): mask[32768] | S[131072]
    unsigned int* mask = (unsigned int*)d_ws;
    float* S = (float*)((char*)d_ws + 32768);

    hipMemsetAsync(mask, 0, 32768, stream);
    k_edges<<<(E + 255) / 256, 256, 0, stream>>>(ei, E, mask);
    k_S    <<<NV, 256, 0, stream>>>(mask, alpha, S);

    hipFuncSetAttribute(reinterpret_cast<const void*>(k_main),
                        hipFuncAttributeMaxDynamicSharedMemorySize, 65536);
    k_main<<<NV, 512, 65536, stream>>>(alpha, w1, b1, w2, b2, eps, mask, S, out);
}

// Round 17
// 62.693 us; speedup vs baseline: 1.3667x; 1.3667x over previous
//
#include <hip/hip_runtime.h>
#include <hip/hip_bf16.h>

#define NV 512
#define NF 64

typedef __attribute__((ext_vector_type(8))) short bf16x8;
typedef __attribute__((ext_vector_type(4))) float f32x4;

union BF8 { bf16x8 v; unsigned u[4]; };

// packed f32 pair -> bf16 pair (RNE); maps to v_cvt_pk_bf16_f32
__device__ __forceinline__ unsigned cvt2(float lo, float hi) {
    __hip_bfloat162 p = __float22bfloat162_rn(float2{lo, hi});
    return *reinterpret_cast<unsigned*>(&p);
}
__device__ __forceinline__ unsigned short cvt1(float x) {
    __hip_bfloat16 b = __float2bfloat16(x);
    return *reinterpret_cast<unsigned short*>(&b);
}

// AwT byte address: row f (1KB each); XOR-swz mixes f bits 0-2 and 3-5.
__device__ __forceinline__ unsigned awt_addr(int f, int jbyte) {
    return (unsigned)((f * 1024 + jbyte) ^ (((f ^ (f >> 3)) & 7) << 4));
}
// wT (transposed weights) in LDS.
__device__ __forceinline__ unsigned wt_addr(int m, int n, int kbyte) {
    return (unsigned)(m * 8192 + ((n * 128 + kbyte) ^ (((n ^ (n >> 3)) & 7) << 4)));
}
// scr slot: slot>>1 distinct over write groups {r,r+4,r+8,r+12}; 2-uniform overall.
__device__ __forceinline__ int slot2(int row) {
    return 2 * (((row >> 2) ^ row) & 3) + (row & 1);
}

__global__ void k_edges(const int* __restrict__ ei, int E, unsigned int* __restrict__ mask) {
    int e = blockIdx.x * 256 + threadIdx.x;
    if (e < E) {
        int s = ei[e];       // src
        int d = ei[E + e];   // dst
        atomicOr(&mask[d * 16 + (s >> 5)], 1u << (s & 31));
    }
}

// 4 waves per v: wave g scans mask words 4g..4g+3; LDS reduce.
__global__ void k_S(const unsigned int* __restrict__ mask, const float* __restrict__ alpha,
                    float* __restrict__ S) {
    __shared__ float red[4][64];
    int v = blockIdx.x;
    int lane = threadIdx.x & 63;
    int g = threadIdx.x >> 6;
    float a0 = 0.f, a1 = 0.f;
    for (int wd = g * 4; wd < g * 4 + 4; ++wd) {
        unsigned bits = mask[v * 16 + wd];
        while (bits) {
            int b0 = __ffs(bits) - 1; bits &= bits - 1;
            float x0 = alpha[((size_t)v * NV + wd * 32 + b0) * NF + lane];
            if (bits) {
                int b1 = __ffs(bits) - 1; bits &= bits - 1;
                a1 += alpha[((size_t)v * NV + wd * 32 + b1) * NF + lane];
            }
            a0 += x0;
        }
    }
    red[g][lane] = a0 + a1;
    __syncthreads();
    if (g == 0)
        S[v * NF + lane] = red[0][lane] + red[1][lane] + red[2][lane] + red[3][lane];
}

// LDS 64KB: AwT bf16 [64 f][512 j] swizzled (GEMM phase); post-GEMM reuse:
//   [0, 16K)   w1T/w2T
//   [16K, 32K) scr bf16 per-wave [16 rows][64], 2KB/wave, slot2 swz
// launch_bounds (512, 2): 256 unified regs/wave. R12 config (best measured) + cvt_pk.
__global__ __launch_bounds__(512, 2) void k_main(
    const float* __restrict__ alpha, const float* __restrict__ w1, const float* __restrict__ b1,
    const float* __restrict__ w2, const float* __restrict__ b2, const float* __restrict__ eps_p,
    const unsigned int* __restrict__ mask, const float* __restrict__ S,
    float* __restrict__ out)
{
    extern __shared__ char smem[];
    const int w    = blockIdx.x;
    const int t    = threadIdx.x;
    const int lane = t & 63;
    const int wid  = t >> 6;
    const int nlo  = lane & 15;
    const int g    = lane >> 4;
    const int mbase = wid * 64;
    const float* src = alpha + (size_t)w * (NV * NF);

    auto stage_half = [&](int i) {
        int task = i * 512 + t;
        int jb = task >> 4;
        int fq = task & 15;
        unsigned ua[4][4];
#pragma unroll
        for (int h = 0; h < 4; ++h) {
            f32x4 r0 = *(const f32x4*)(src + (size_t)(jb * 8 + 2 * h) * NF + fq * 4);
            f32x4 r1 = *(const f32x4*)(src + (size_t)(jb * 8 + 2 * h + 1) * NF + fq * 4);
#pragma unroll
            for (int c = 0; c < 4; ++c)
                ua[c][h] = cvt2(r0[c], r1[c]);    // v_cvt_pk_bf16_f32
        }
#pragma unroll
        for (int c = 0; c < 4; ++c) {
            BF8 p;
            p.u[0] = ua[c][0]; p.u[1] = ua[c][1]; p.u[2] = ua[c][2]; p.u[3] = ua[c][3];
            *(bf16x8*)(smem + awt_addr(fq * 4 + c, jb * 16)) = p.v;
        }
    };

    f32x4 acc[4][4];

    // phase 1a: stage half0 (HBM/L3 loads first)
    stage_half(0);

    // phase 1b: preload ALL mask words (L2-hot) — cover the whole GEMM
    uint4 qm[4][4];   // [mi][kq]
#pragma unroll
    for (int mi = 0; mi < 4; ++mi)
#pragma unroll
        for (int kq = 0; kq < 4; ++kq)
            qm[mi][kq] = *(const uint4*)(mask + (size_t)(mbase + mi * 16 + nlo) * 16 + kq * 4);

    // phase 1c: init acc from S (C-in of first MFMA)
#pragma unroll
    for (int mi = 0; mi < 4; ++mi)
#pragma unroll
        for (int nt = 0; nt < 4; ++nt)
#pragma unroll
            for (int r = 0; r < 4; ++r)
                acc[mi][nt][r] = S[(size_t)(mbase + mi * 16 + g * 4 + r) * NF + nt * 16 + nlo];

    __syncthreads();

    auto gemm_q = [&](int kq) {
#pragma unroll
        for (int kr = 0; kr < 4; ++kr) {
            const int kk = kq * 4 + kr;
            const unsigned wv[4] = {
                (&qm[0][kq].x)[kr], (&qm[1][kq].x)[kr],
                (&qm[2][kq].x)[kr], (&qm[3][kq].x)[kr] };
            BF8 afr[4];
#pragma unroll
            for (int mi = 0; mi < 4; ++mi) {
                unsigned byteb = (wv[mi] >> (g * 8)) & 0xFFu;
#pragma unroll
                for (int h = 0; h < 4; ++h) {
                    unsigned b0 = (byteb >> (2 * h)) & 1u;
                    unsigned b1 = (byteb >> (2 * h + 1)) & 1u;
                    afr[mi].u[h] = (b0 ? 0x3F80u : 0u) | (b1 ? 0x3F800000u : 0u);
                }
            }
#pragma unroll
            for (int nt = 0; nt < 4; ++nt) {
                bf16x8 bfr = *(const bf16x8*)(smem + awt_addr(nt * 16 + nlo, kk * 64 + g * 16));
#pragma unroll
                for (int mi = 0; mi < 4; ++mi)
                    acc[mi][nt] = __builtin_amdgcn_mfma_f32_16x16x32_bf16(afr[mi].v, bfr, acc[mi][nt], 0, 0, 0);
            }
        }
    };

    // pipeline: {stage half1 || GEMM kq0-1 (half0 only)} | barrier | GEMM kq2-3
    stage_half(1);
    gemm_q(0); gemm_q(1);
    __syncthreads();
    gemm_q(2); gemm_q(3);
    __syncthreads();          // AwT dead; reuse for wT + scr

    if (t < 256) {
        int m  = t >> 7;
        int sub = t & 127;
        int jb = sub >> 4;
        int fq = sub & 15;
        const float* wsrc = m ? w2 : w1;
        unsigned ua[4][4];
#pragma unroll
        for (int h = 0; h < 4; ++h) {
            f32x4 r0 = *(const f32x4*)(wsrc + (size_t)(jb * 8 + 2 * h) * NF + fq * 4);
            f32x4 r1 = *(const f32x4*)(wsrc + (size_t)(jb * 8 + 2 * h + 1) * NF + fq * 4);
#pragma unroll
            for (int c = 0; c < 4; ++c)
                ua[c][h] = cvt2(r0[c], r1[c]);
        }
#pragma unroll
        for (int c = 0; c < 4; ++c) {
            BF8 p;
            p.u[0] = ua[c][0]; p.u[1] = ua[c][1]; p.u[2] = ua[c][2]; p.u[3] = ua[c][3];
            *(bf16x8*)(smem + wt_addr(m, fq * 4 + c, jb * 16)) = p.v;
        }
    }
    float b1v[4], b2v[4];
#pragma unroll
    for (int nt = 0; nt < 4; ++nt) {
        b1v[nt] = b1[nt * 16 + nlo];
        b2v[nt] = b2[nt * 16 + nlo];
    }
    const float ceps = 1.0f + eps_p[0];
    __syncthreads();

    char* myscr = smem + 16384 + wid * 2048;
#pragma unroll
    for (int mi = 0; mi < 4; ++mi) {
        int v0 = mbase + mi * 16;
        float rvv[4][4];
#pragma unroll
        for (int nt = 0; nt < 4; ++nt)
#pragma unroll
            for (int r = 0; r < 4; ++r)
                rvv[nt][r] = alpha[((size_t)(v0 + g * 4 + r) * NV + w) * NF + nt * 16 + nlo];
#pragma unroll
        for (int nt = 0; nt < 4; ++nt)
#pragma unroll
            for (int r = 0; r < 4; ++r) {
                float pre = acc[mi][nt][r] + ceps * rvv[nt][r];
                int row = g * 4 + r;
                *(unsigned short*)(myscr + row * 128 + ((2 * (nt * 16 + nlo)) ^ (slot2(row) << 4))) = cvt1(pre);
            }
        bf16x8 a0 = *(const bf16x8*)(myscr + nlo * 128 + ((g * 16) ^ (slot2(nlo) << 4)));
        bf16x8 a1 = *(const bf16x8*)(myscr + nlo * 128 + ((g * 16 + 64) ^ (slot2(nlo) << 4)));
        f32x4 accm[4];
#pragma unroll
        for (int nt = 0; nt < 4; ++nt) {
            bf16x8 wf0 = *(const bf16x8*)(smem + wt_addr(0, nt * 16 + nlo, g * 16));
            bf16x8 wf1 = *(const bf16x8*)(smem + wt_addr(0, nt * 16 + nlo, 64 + g * 16));
            f32x4 z = {0.f, 0.f, 0.f, 0.f};
            z = __builtin_amdgcn_mfma_f32_16x16x32_bf16(a0, wf0, z, 0, 0, 0);
            z = __builtin_amdgcn_mfma_f32_16x16x32_bf16(a1, wf1, z, 0, 0, 0);
            accm[nt] = z;
        }
#pragma unroll
        for (int nt = 0; nt < 4; ++nt)
#pragma unroll
            for (int r = 0; r < 4; ++r) {
                float hv = accm[nt][r] + b1v[nt];
                hv = hv > 0.f ? hv : 0.f;
                int row = g * 4 + r;
                *(unsigned short*)(myscr + row * 128 + ((2 * (nt * 16 + nlo)) ^ (slot2(row) << 4))) = cvt1(hv);
            }
        bf16x8 h0 = *(const bf16x8*)(myscr + nlo * 128 + ((g * 16) ^ (slot2(nlo) << 4)));
        bf16x8 h1 = *(const bf16x8*)(myscr + nlo * 128 + ((g * 16 + 64) ^ (slot2(nlo) << 4)));
#pragma unroll
        for (int nt = 0; nt < 4; ++nt) {
            bf16x8 wf0 = *(const bf16x8*)(smem + wt_addr(1, nt * 16 + nlo, g * 16));
            bf16x8 wf1 = *(const bf16x8*)(smem + wt_addr(1, nt * 16 + nlo, 64 + g * 16));
            f32x4 z = {0.f, 0.f, 0.f, 0.f};
            z = __builtin_amdgcn_mfma_f32_16x16x32_bf16(h0, wf0, z, 0, 0, 0);
            z = __builtin_amdgcn_mfma_f32_16x16x32_bf16(h1, wf1, z, 0, 0, 0);
#pragma unroll
            for (int r = 0; r < 4; ++r) {
                int vv = v0 + g * 4 + r;
                out[((size_t)vv * NV + w) * NF + nt * 16 + nlo] = z[r] + b2v[nt];
            }
        }
    }
}

extern "C" void kernel_launch(void* const* d_in, const int* in_sizes, int n_in,
                              void* d_out, int out_size, void* d_ws, size_t ws_size,
                              hipStream_t stream) {
    const float* alpha = (const float*)d_in[0];
    const int*   ei    = (const int*)d_in[1];
    const float* w1    = (const float*)d_in[2];
    const float* b1    = (const float*)d_in[3];
    const float* w2    = (const float*)d_in[4];
    const float* b2    = (const float*)d_in[5];
    const float* eps   = (const float*)d_in[6];
    float* out = (float*)d_out;
    int E = in_sizes[1] / 2;

    // ws layout (bytes): mask[32768] | S[131072]
    unsigned int* mask = (unsigned int*)d_ws;
    float* S = (float*)((char*)d_ws + 32768);

    hipMemsetAsync(mask, 0, 32768, stream);
    k_edges<<<(E + 255) / 256, 256, 0, stream>>>(ei, E, mask);
    k_S    <<<NV, 256, 0, stream>>>(mask, alpha, S);

    hipFuncSetAttribute(reinterpret_cast<const void*>(k_main),
                        hipFuncAttributeMaxDynamicSharedMemorySize, 65536);
    k_main<<<NV, 512, 65536, stream>>>(alpha, w1, b1, w2, b2, eps, mask, S, out);
}